// Round 9
// baseline (311.181 us; speedup 1.0000x reference)
//
#include <hip/hip_runtime.h>
#include <hip/hip_bf16.h>

// Problem constants (B=4, N=2048, C=768, H=12, D=64)
#define BB 4
#define NN 2048
#define CC 768
#define HH 12
#define DD 64

typedef __bf16 bf16;
typedef __attribute__((ext_vector_type(8))) __bf16 bf16x8;
typedef __attribute__((ext_vector_type(4))) __bf16 bf16x4;
typedef __attribute__((ext_vector_type(4))) float f32x4;

// ---- workspace layout (bf16 elems) ----------------------------------------
#define SZ_X    (BB * NN * CC)              // 6291456
#define SZ_QKVW (3 * CC * CC)               // 1769472
#define SZ_PW   (CC * CC)                   // 589824
#define SZ_QKV  ((size_t)BB * NN * 3 * CC)  // 18874368

#define OFF_X    0
#define OFF_VT   0                          // aliases xb (x dead after QKV GEMM)
#define OFF_QW   (OFF_X + SZ_X)
#define OFF_PW   (OFF_QW + SZ_QKVW)
#define OFF_QKV  (OFF_PW + SZ_PW)           // end = 27525120 elems = 55.1 MB

// Direct-to-LDS 16B DMA; source chunk XOR-swizzled to kill read conflicts.
__device__ __forceinline__ void async16(const bf16* g, bf16* l) {
    __builtin_amdgcn_global_load_lds(
        (const __attribute__((address_space(1))) unsigned int*)g,
        (__attribute__((address_space(3))) unsigned int*)l, 16, 0, 0);
}

// ---------------------------------------------------------------------------
__global__ __launch_bounds__(256) void convert3(
    const float* __restrict__ x, const float* __restrict__ qkvw,
    const float* __restrict__ pw, bf16* __restrict__ ws) {
    const int t = blockIdx.x * 256 + threadIdx.x;
    const int S = gridDim.x * 256;
    for (int i = t; i < SZ_X;    i += S) ws[OFF_X + i]  = (bf16)x[i];
    for (int i = t; i < SZ_QKVW; i += S) ws[OFF_QW + i] = (bf16)qkvw[i];
    for (int i = t; i < SZ_PW;   i += S) ws[OFF_PW + i] = (bf16)pw[i];
}

// ---------------------------------------------------------------------------
// m97-style GEMM: 128x128 tile, BK=64, DMA staging, swizzled LDS (unchanged).
// ---------------------------------------------------------------------------
template <bool HAS_BIAS, typename OutT>
__global__ __launch_bounds__(256) void gemm128(
    const bf16* __restrict__ A, int lda, const bf16* __restrict__ W,
    const float* __restrict__ bias, OutT* __restrict__ C,
    int M, int Nn, int K) {
    __shared__ __align__(16) bf16 As[128 * 64];
    __shared__ __align__(16) bf16 Bs[128 * 64];
    const int tid  = threadIdx.x;
    const int wave = tid >> 6;
    const int lane = tid & 63;
    const int quad = lane >> 4;
    const int l16  = lane & 15;
    const int m0 = blockIdx.y * 128;
    const int n0 = blockIdx.x * 128;
    const int wm = (wave >> 1) * 64;
    const int wn = (wave & 1) * 64;
    const int srow = lane >> 3;
    const int swz  = (lane & 7) ^ srow;

    f32x4 acc[4][4];
#pragma unroll
    for (int i = 0; i < 4; ++i)
#pragma unroll
        for (int j = 0; j < 4; ++j) acc[i][j] = (f32x4){0.f, 0.f, 0.f, 0.f};

    for (int k0 = 0; k0 < K; k0 += 64) {
#pragma unroll
        for (int i = 0; i < 4; ++i) {
            int row = i * 32 + wave * 8 + srow;
            async16(A + (size_t)(m0 + row) * lda + k0 + swz * 8,
                    &As[(i * 32 + wave * 8) * 64]);
            async16(W + (size_t)(n0 + row) * K + k0 + swz * 8,
                    &Bs[(i * 32 + wave * 8) * 64]);
        }
        __syncthreads();
#pragma unroll
        for (int kk = 0; kk < 2; ++kk) {
            const int slot = ((kk * 4 + quad) ^ (l16 & 7)) * 8;
            bf16x8 af[4], bf[4];
#pragma unroll
            for (int mt = 0; mt < 4; ++mt)
                af[mt] = *(const bf16x8*)(&As[(wm + mt * 16 + l16) * 64 + slot]);
#pragma unroll
            for (int nt = 0; nt < 4; ++nt)
                bf[nt] = *(const bf16x8*)(&Bs[(wn + nt * 16 + l16) * 64 + slot]);
#pragma unroll
            for (int mt = 0; mt < 4; ++mt)
#pragma unroll
                for (int nt = 0; nt < 4; ++nt)
                    acc[mt][nt] = __builtin_amdgcn_mfma_f32_16x16x32_bf16(
                        af[mt], bf[nt], acc[mt][nt], 0, 0, 0);
        }
        __syncthreads();
    }
#pragma unroll
    for (int mt = 0; mt < 4; ++mt)
#pragma unroll
        for (int nt = 0; nt < 4; ++nt)
#pragma unroll
            for (int r = 0; r < 4; ++r) {
                int row = m0 + wm + mt * 16 + quad * 4 + r;
                int col = n0 + wn + nt * 16 + l16;
                float v = acc[mt][nt][r];
                if (HAS_BIAS) v += bias[col];
                C[(size_t)row * Nn + col] = (OutT)v;
            }
}

// ---------------------------------------------------------------------------
// Transpose v-slice of qkv [B*N][3C] -> Vt [B*H][D][N]  (unchanged, verified)
// ---------------------------------------------------------------------------
__global__ __launch_bounds__(256) void transpose_v(
    const bf16* __restrict__ qkv, bf16* __restrict__ Vt) {
    __shared__ __align__(16) bf16 Ts[64 * 64];
    const int t = threadIdx.x;
    const int bh = blockIdx.x;
    const int kt = blockIdx.y;
    const int b = bh / HH, h = bh % HH;
    const size_t rs = 3 * CC;
    const bf16* src = qkv + (size_t)b * NN * rs + 2 * CC + h * DD;
    {
        const int keyl = t >> 2;
        const int d0   = (t & 3) * 16;
#pragma unroll
        for (int half = 0; half < 2; ++half) {
            int dd = d0 + half * 8;
            bf16x8 v = *(const bf16x8*)(src + (size_t)(kt * 64 + keyl) * rs + dd);
            int dc = dd >> 3;
            *(bf16x8*)(&Ts[keyl * 64 + ((dc ^ (keyl >> 3)) * 8)]) = v;
        }
    }
    __syncthreads();
#pragma unroll
    for (int p = 0; p < 2; ++p) {
        const int d  = p * 32 + (t >> 3);
        const int kc = (t & 7) * 8;
        bf16x8 v;
#pragma unroll
        for (int j = 0; j < 8; ++j) {
            int key = kc + j;
            v[j] = Ts[key * 64 + (((d >> 3) ^ (key >> 3)) * 8 + (d & 7))];
        }
        *(bf16x8*)(Vt + ((size_t)bh * DD + d) * NN + kt * 64 + kc) = v;
    }
}

// ---------------------------------------------------------------------------
// RMSNorm + RoPE in-place on q,k slices — unchanged (verified).
// ---------------------------------------------------------------------------
__global__ __launch_bounds__(256) void norm_rope(
    bf16* __restrict__ qkv, const float* __restrict__ cosb,
    const float* __restrict__ sinb, const float* __restrict__ qw,
    const float* __restrict__ kw) {
    const int lane = threadIdx.x & 63;
    const int wave = threadIdx.x >> 6;
    const int job = blockIdx.x * 4 + wave;
    const int h = job % HH;
    const int s = (job / HH) & 1;
    const int bn = job / (2 * HH);
    const int n = bn % NN;

    bf16* row = qkv + (size_t)bn * (3 * CC) + s * CC + h * DD;
    float x = (float)row[lane];
    float ss = x * x;
#pragma unroll
    for (int m = 32; m >= 1; m >>= 1) ss += __shfl_xor(ss, m, 64);
    float r = rsqrtf(ss * (1.0f / 64.0f) + 1e-6f);
    x = x * r * ((s == 0) ? qw[lane] : kw[lane]);
    float xp = __shfl_xor(x, 32, 64);
    int j = lane & 31;
    float c  = cosb[n * 32 + j];
    float si = sinb[n * 32 + j];
    x = (lane < 32) ? (x * c - xp * si) : (x * c + xp * si);
    row[lane] = (bf16)x;
}

// ---------------------------------------------------------------------------
// Flash attention, static-max softmax (|s|<=128 bound — see R7).
// OPERAND-SWAPPED QK: mfma(kf, qf) computes S^T; A/B lane maps are identical
// so the fragment reads are unchanged. Lane then holds fixed q = f*16+l16,
// keys nt*16+quad*4+r: 4 consecutive keys -> PACKED b64 P-stores, scalar
// lsum per frag (quad-reduce deferred to epilogue). K-tile = 128 (2 V panels
// per barrier pair). PV side identical to R8.
// ---------------------------------------------------------------------------
__global__ __launch_bounds__(256) void flash_attn(
    const bf16* __restrict__ qkv, const bf16* __restrict__ Vt,
    bf16* __restrict__ Oqkv) {
    __shared__ __align__(16) bf16 Ks[128 * 64];      // [key][d] swizzled
    __shared__ __align__(16) bf16 Vs[2][64 * 64];    // [panel][d][key] swizzled
    __shared__ __align__(16) bf16 Ps[4][32 * 72];    // per-wave [q][key], padded
    const int tid  = threadIdx.x;
    const int wave = tid >> 6;
    const int lane = tid & 63;
    const int quad = lane >> 4;
    const int l16  = lane & 15;
    const int r7   = l16 & 7;
    const int bh = blockIdx.x;
    const int qt = blockIdx.y;
    const int b = bh / HH, h = bh % HH;
    const size_t rs = 3 * CC;
    const bf16* Qb  = qkv + (size_t)b * NN * rs + h * DD;
    const bf16* Kb  = Qb + CC;
    const bf16* Vtb = Vt + (size_t)bh * DD * NN;
    const float CEXP  = 0.125f * 1.44269504f;
    const float SHIFT = 23.0831168f;          // 128 * 0.125 * log2(e)

    bf16x8 qf[2][2];
#pragma unroll
    for (int f = 0; f < 2; ++f) {
        const int qrow = qt * 128 + wave * 32 + f * 16 + l16;
#pragma unroll
        for (int hf = 0; hf < 2; ++hf)
            qf[f][hf] = *(const bf16x8*)(Qb + (size_t)qrow * rs + hf * 32 + quad * 8);
    }

    f32x4 accO[2][4];
#pragma unroll
    for (int f = 0; f < 2; ++f)
#pragma unroll
        for (int i = 0; i < 4; ++i) accO[f][i] = (f32x4){0.f, 0.f, 0.f, 0.f};
    float lsum[2] = {0.f, 0.f};

    const int srow = lane >> 3;
    const int swz  = (lane & 7) ^ srow;

    for (int kt = 0; kt < NN / 128; ++kt) {
        // stage 128 K-rows (4 issues) + 2 V^T panels (2x2 issues)
#pragma unroll
        for (int i = 0; i < 4; ++i) {
            int row = i * 32 + wave * 8 + srow;
            async16(Kb + (size_t)(kt * 128 + row) * rs + swz * 8,
                    &Ks[(i * 32 + wave * 8) * 64]);
        }
#pragma unroll
        for (int p = 0; p < 2; ++p)
#pragma unroll
            for (int i = 0; i < 2; ++i) {
                int row = i * 32 + wave * 8 + srow;
                async16(Vtb + (size_t)row * NN + kt * 128 + p * 64 + swz * 8,
                        &Vs[p][(i * 32 + wave * 8) * 64]);
            }
        __syncthreads();

#pragma unroll
        for (int p = 0; p < 2; ++p) {
            // S^T = (Q K^T)^T via swapped operands
            f32x4 s[2][4];
#pragma unroll
            for (int nt = 0; nt < 4; ++nt) {
                const int row = p * 64 + nt * 16 + l16;
                bf16x8 kf0 = *(const bf16x8*)(&Ks[row * 64 + (quad ^ r7) * 8]);
                bf16x8 kf1 = *(const bf16x8*)(&Ks[row * 64 + ((quad + 4) ^ r7) * 8]);
#pragma unroll
                for (int f = 0; f < 2; ++f) {
                    f32x4 z = (f32x4){0.f, 0.f, 0.f, 0.f};
                    z = __builtin_amdgcn_mfma_f32_16x16x32_bf16(kf0, qf[f][0], z, 0, 0, 0);
                    s[f][nt] = __builtin_amdgcn_mfma_f32_16x16x32_bf16(kf1, qf[f][1], z, 0, 0, 0);
                }
            }

            // p = exp2(s*CEXP - SHIFT); packed b64 stores (4 consecutive keys)
#pragma unroll
            for (int f = 0; f < 2; ++f)
#pragma unroll
                for (int nt = 0; nt < 4; ++nt) {
                    bf16x4 pk;
#pragma unroll
                    for (int r = 0; r < 4; ++r) {
                        float pv = exp2f(s[f][nt][r] * CEXP - SHIFT);
                        lsum[f] += pv;
                        pk[r] = (bf16)pv;
                    }
                    *(bf16x4*)(&Ps[wave][(f * 16 + l16) * 72 + nt * 16 + quad * 4]) = pk;
                }
            // Ps wave-private: wave-local DS drain + compiler fence
            __asm__ volatile("s_waitcnt lgkmcnt(0)" ::: "memory");

            bf16x8 pf0[2], pf1[2];
#pragma unroll
            for (int f = 0; f < 2; ++f) {
                pf0[f] = *(const bf16x8*)(&Ps[wave][(f * 16 + l16) * 72 + quad * 8]);
                pf1[f] = *(const bf16x8*)(&Ps[wave][(f * 16 + l16) * 72 + 32 + quad * 8]);
            }
#pragma unroll
            for (int nt = 0; nt < 4; ++nt) {
                const int rowd = nt * 16 + l16;
                bf16x8 vf0 = *(const bf16x8*)(&Vs[p][rowd * 64 + (quad ^ r7) * 8]);
                bf16x8 vf1 = *(const bf16x8*)(&Vs[p][rowd * 64 + ((quad + 4) ^ r7) * 8]);
#pragma unroll
                for (int f = 0; f < 2; ++f) {
                    accO[f][nt] = __builtin_amdgcn_mfma_f32_16x16x32_bf16(pf0[f], vf0, accO[f][nt], 0, 0, 0);
                    accO[f][nt] = __builtin_amdgcn_mfma_f32_16x16x32_bf16(pf1[f], vf1, accO[f][nt], 0, 0, 0);
                }
            }
            // drain Ps reads before next panel overwrites (wave-local)
            __asm__ volatile("s_waitcnt lgkmcnt(0)" ::: "memory");
        }
        __syncthreads();
    }

    // lsum: reduce over the 4 quads sharing l16 (lane's q = f*16+l16)
#pragma unroll
    for (int f = 0; f < 2; ++f) {
        lsum[f] += __shfl_xor(lsum[f], 16, 64);
        lsum[f] += __shfl_xor(lsum[f], 32, 64);
    }

    // epilogue: accO row q = f*16+quad*4+r; fetch 1/lsum from lane quad*4+r
#pragma unroll
    for (int f = 0; f < 2; ++f)
#pragma unroll
        for (int r = 0; r < 4; ++r) {
            float inv = 1.0f / __shfl(lsum[f], quad * 4 + r, 64);
            int n = qt * 128 + wave * 32 + f * 16 + quad * 4 + r;
#pragma unroll
            for (int nt = 0; nt < 4; ++nt) {
                int col = h * DD + nt * 16 + l16;
                Oqkv[(size_t)(b * NN + n) * rs + 2 * CC + col] = (bf16)(accO[f][nt][r] * inv);
            }
        }
}

// ---------------------------------------------------------------------------
extern "C" void kernel_launch(void* const* d_in, const int* in_sizes, int n_in,
                              void* d_out, int out_size, void* d_ws, size_t ws_size,
                              hipStream_t stream) {
    const float* x     = (const float*)d_in[0];
    const float* cosb  = (const float*)d_in[1];
    const float* sinb  = (const float*)d_in[2];
    const float* qkv_w = (const float*)d_in[3];
    const float* qnw   = (const float*)d_in[4];
    const float* knw   = (const float*)d_in[5];
    const float* pw    = (const float*)d_in[6];
    const float* pb    = (const float*)d_in[7];
    float* out = (float*)d_out;

    bf16* ws  = (bf16*)d_ws;
    bf16* xb  = ws + OFF_X;
    bf16* vt  = ws + OFF_VT;   // reuses xb after QKV GEMM
    bf16* qwb = ws + OFF_QW;
    bf16* pwb = ws + OFF_PW;
    bf16* qkv = ws + OFF_QKV;

    const int M = BB * NN;  // 8192

    // 0) cast MFMA operands to bf16
    convert3<<<1024, 256, 0, stream>>>(x, qkv_w, pw, ws);

    // 1) QKV projection -> qkv [B*N][3C] (bf16); 128x128 tiles
    dim3 g1(3 * CC / 128, M / 128);
    gemm128<false, bf16><<<g1, 256, 0, stream>>>(xb, CC, qwb, nullptr, qkv, M, 3 * CC, CC);

    // 2) transpose v-slice -> Vt [B*H][D][N]
    dim3 g2(BB * HH, NN / 64);
    transpose_v<<<g2, 256, 0, stream>>>(qkv, vt);

    // 3) RMSNorm + RoPE in place on q,k
    norm_rope<<<(BB * NN * 2 * HH) / 4, 256, 0, stream>>>(qkv, cosb, sinb, qnw, knw);

    // 4) Flash attention -> v-slice of qkv; 128 q-rows, 128-key tiles
    dim3 g4(BB * HH, NN / 128);
    flash_attn<<<g4, 256, 0, stream>>>(qkv, vt, qkv);

    // 5) Output projection (+fp32 bias) -> d_out; A = v-slice, lda = 3C
    dim3 g5(CC / 128, M / 128);
    gemm128<true, float><<<g5, 256, 0, stream>>>(qkv + 2 * CC, 3 * CC, pwb, pb, out, M, CC, CC);
}

// Round 10
// 251.374 us; speedup vs baseline: 1.2379x; 1.2379x over previous
//
#include <hip/hip_runtime.h>
#include <hip/hip_bf16.h>

// Problem constants (B=4, N=2048, C=768, H=12, D=64)
#define BB 4
#define NN 2048
#define CC 768
#define HH 12
#define DD 64

typedef __bf16 bf16;
typedef __attribute__((ext_vector_type(8))) __bf16 bf16x8;
typedef __attribute__((ext_vector_type(4))) __bf16 bf16x4;
typedef __attribute__((ext_vector_type(4))) float f32x4;

// ---- workspace layout (bf16 elems) ----------------------------------------
#define SZ_X    (BB * NN * CC)              // 6291456
#define SZ_QKVW (3 * CC * CC)               // 1769472
#define SZ_PW   (CC * CC)                   // 589824
#define SZ_QKV  ((size_t)BB * NN * 3 * CC)  // 18874368

#define OFF_X    0
#define OFF_VT   0                          // aliases xb (x dead after QKV GEMM)
#define OFF_QW   (OFF_X + SZ_X)
#define OFF_PW   (OFF_QW + SZ_QKVW)
#define OFF_QKV  (OFF_PW + SZ_PW)           // end = 27525120 elems = 55.1 MB

// Direct-to-LDS 16B DMA; source chunk XOR-swizzled to kill read conflicts.
__device__ __forceinline__ void async16(const bf16* g, bf16* l) {
    __builtin_amdgcn_global_load_lds(
        (const __attribute__((address_space(1))) unsigned int*)g,
        (__attribute__((address_space(3))) unsigned int*)l, 16, 0, 0);
}

// ---------------------------------------------------------------------------
__global__ __launch_bounds__(256) void convert3(
    const float* __restrict__ x, const float* __restrict__ qkvw,
    const float* __restrict__ pw, bf16* __restrict__ ws) {
    const int t = blockIdx.x * 256 + threadIdx.x;
    const int S = gridDim.x * 256;
    for (int i = t; i < SZ_X;    i += S) ws[OFF_X + i]  = (bf16)x[i];
    for (int i = t; i < SZ_QKVW; i += S) ws[OFF_QW + i] = (bf16)qkvw[i];
    for (int i = t; i < SZ_PW;   i += S) ws[OFF_PW + i] = (bf16)pw[i];
}

// ---------------------------------------------------------------------------
// m97-style GEMM: 128x128 tile, BK=64, DMA staging, swizzled LDS (unchanged).
// ---------------------------------------------------------------------------
template <bool HAS_BIAS, typename OutT>
__global__ __launch_bounds__(256) void gemm128(
    const bf16* __restrict__ A, int lda, const bf16* __restrict__ W,
    const float* __restrict__ bias, OutT* __restrict__ C,
    int M, int Nn, int K) {
    __shared__ __align__(16) bf16 As[128 * 64];
    __shared__ __align__(16) bf16 Bs[128 * 64];
    const int tid  = threadIdx.x;
    const int wave = tid >> 6;
    const int lane = tid & 63;
    const int quad = lane >> 4;
    const int l16  = lane & 15;
    const int m0 = blockIdx.y * 128;
    const int n0 = blockIdx.x * 128;
    const int wm = (wave >> 1) * 64;
    const int wn = (wave & 1) * 64;
    const int srow = lane >> 3;
    const int swz  = (lane & 7) ^ srow;

    f32x4 acc[4][4];
#pragma unroll
    for (int i = 0; i < 4; ++i)
#pragma unroll
        for (int j = 0; j < 4; ++j) acc[i][j] = (f32x4){0.f, 0.f, 0.f, 0.f};

    for (int k0 = 0; k0 < K; k0 += 64) {
#pragma unroll
        for (int i = 0; i < 4; ++i) {
            int row = i * 32 + wave * 8 + srow;
            async16(A + (size_t)(m0 + row) * lda + k0 + swz * 8,
                    &As[(i * 32 + wave * 8) * 64]);
            async16(W + (size_t)(n0 + row) * K + k0 + swz * 8,
                    &Bs[(i * 32 + wave * 8) * 64]);
        }
        __syncthreads();
#pragma unroll
        for (int kk = 0; kk < 2; ++kk) {
            const int slot = ((kk * 4 + quad) ^ (l16 & 7)) * 8;
            bf16x8 af[4], bf[4];
#pragma unroll
            for (int mt = 0; mt < 4; ++mt)
                af[mt] = *(const bf16x8*)(&As[(wm + mt * 16 + l16) * 64 + slot]);
#pragma unroll
            for (int nt = 0; nt < 4; ++nt)
                bf[nt] = *(const bf16x8*)(&Bs[(wn + nt * 16 + l16) * 64 + slot]);
#pragma unroll
            for (int mt = 0; mt < 4; ++mt)
#pragma unroll
                for (int nt = 0; nt < 4; ++nt)
                    acc[mt][nt] = __builtin_amdgcn_mfma_f32_16x16x32_bf16(
                        af[mt], bf[nt], acc[mt][nt], 0, 0, 0);
        }
        __syncthreads();
    }
#pragma unroll
    for (int mt = 0; mt < 4; ++mt)
#pragma unroll
        for (int nt = 0; nt < 4; ++nt)
#pragma unroll
            for (int r = 0; r < 4; ++r) {
                int row = m0 + wm + mt * 16 + quad * 4 + r;
                int col = n0 + wn + nt * 16 + l16;
                float v = acc[mt][nt][r];
                if (HAS_BIAS) v += bias[col];
                C[(size_t)row * Nn + col] = (OutT)v;
            }
}

// ---------------------------------------------------------------------------
// Transpose v-slice of qkv [B*N][3C] -> Vt [B*H][D][N]  (unchanged, verified)
// ---------------------------------------------------------------------------
__global__ __launch_bounds__(256) void transpose_v(
    const bf16* __restrict__ qkv, bf16* __restrict__ Vt) {
    __shared__ __align__(16) bf16 Ts[64 * 64];
    const int t = threadIdx.x;
    const int bh = blockIdx.x;
    const int kt = blockIdx.y;
    const int b = bh / HH, h = bh % HH;
    const size_t rs = 3 * CC;
    const bf16* src = qkv + (size_t)b * NN * rs + 2 * CC + h * DD;
    {
        const int keyl = t >> 2;
        const int d0   = (t & 3) * 16;
#pragma unroll
        for (int half = 0; half < 2; ++half) {
            int dd = d0 + half * 8;
            bf16x8 v = *(const bf16x8*)(src + (size_t)(kt * 64 + keyl) * rs + dd);
            int dc = dd >> 3;
            *(bf16x8*)(&Ts[keyl * 64 + ((dc ^ (keyl >> 3)) * 8)]) = v;
        }
    }
    __syncthreads();
#pragma unroll
    for (int p = 0; p < 2; ++p) {
        const int d  = p * 32 + (t >> 3);
        const int kc = (t & 7) * 8;
        bf16x8 v;
#pragma unroll
        for (int j = 0; j < 8; ++j) {
            int key = kc + j;
            v[j] = Ts[key * 64 + (((d >> 3) ^ (key >> 3)) * 8 + (d & 7))];
        }
        *(bf16x8*)(Vt + ((size_t)bh * DD + d) * NN + kt * 64 + kc) = v;
    }
}

// ---------------------------------------------------------------------------
// RMSNorm + RoPE in-place on q,k.  NEW: q-rows are additionally scaled by
// CEXP = 0.125*log2(e) in fp32 before the single bf16 rounding, so QK^T
// scores exit the MFMA already in exp2-domain (flash does p = exp2(s), no
// per-element fma, no shift — softmax is shift-invariant and the constant
// cancels in accO/lsum; range |s'| <= 23.1 is safe in bf16/fp32).
// ---------------------------------------------------------------------------
__global__ __launch_bounds__(256) void norm_rope(
    bf16* __restrict__ qkv, const float* __restrict__ cosb,
    const float* __restrict__ sinb, const float* __restrict__ qw,
    const float* __restrict__ kw) {
    const int lane = threadIdx.x & 63;
    const int wave = threadIdx.x >> 6;
    const int job = blockIdx.x * 4 + wave;
    const int h = job % HH;
    const int s = (job / HH) & 1;
    const int bn = job / (2 * HH);
    const int n = bn % NN;

    bf16* row = qkv + (size_t)bn * (3 * CC) + s * CC + h * DD;
    float x = (float)row[lane];
    float ss = x * x;
#pragma unroll
    for (int m = 32; m >= 1; m >>= 1) ss += __shfl_xor(ss, m, 64);
    float r = rsqrtf(ss * (1.0f / 64.0f) + 1e-6f);
    x = x * r * ((s == 0) ? qw[lane] : kw[lane]);
    float xp = __shfl_xor(x, 32, 64);
    int j = lane & 31;
    float c  = cosb[n * 32 + j];
    float si = sinb[n * 32 + j];
    x = (lane < 32) ? (x * c - xp * si) : (x * c + xp * si);
    if (s == 0) x *= 0.18033688f;   // CEXP folded into q (fp32, pre-rounding)
    row[lane] = (bf16)x;
}

// ---------------------------------------------------------------------------
// Flash attention. 64-key tiles (LDS 34.8KB -> 4 blocks/CU), operand-swapped
// QK (S^T: lane q = f*16+l16, keys nt*16+quad*4+r -> packed b64 P-stores),
// raw v_exp_f32, no fma/shift in the softmax block (folded into norm_rope).
// ---------------------------------------------------------------------------
__global__ __launch_bounds__(256) void flash_attn(
    const bf16* __restrict__ qkv, const bf16* __restrict__ Vt,
    bf16* __restrict__ Oqkv) {
    __shared__ __align__(16) bf16 Ks[64 * 64];       // [key][d] swizzled
    __shared__ __align__(16) bf16 Vs[64 * 64];       // [d][key] swizzled
    __shared__ __align__(16) bf16 Ps[4][32 * 72];    // per-wave [q][key], padded
    const int tid  = threadIdx.x;
    const int wave = tid >> 6;
    const int lane = tid & 63;
    const int quad = lane >> 4;
    const int l16  = lane & 15;
    const int r7   = l16 & 7;
    const int bh = blockIdx.x;
    const int qt = blockIdx.y;
    const int b = bh / HH, h = bh % HH;
    const size_t rs = 3 * CC;
    const bf16* Qb  = qkv + (size_t)b * NN * rs + h * DD;
    const bf16* Kb  = Qb + CC;
    const bf16* Vtb = Vt + (size_t)bh * DD * NN;

    bf16x8 qf[2][2];
#pragma unroll
    for (int f = 0; f < 2; ++f) {
        const int qrow = qt * 128 + wave * 32 + f * 16 + l16;
#pragma unroll
        for (int hf = 0; hf < 2; ++hf)
            qf[f][hf] = *(const bf16x8*)(Qb + (size_t)qrow * rs + hf * 32 + quad * 8);
    }

    f32x4 accO[2][4];
#pragma unroll
    for (int f = 0; f < 2; ++f)
#pragma unroll
        for (int i = 0; i < 4; ++i) accO[f][i] = (f32x4){0.f, 0.f, 0.f, 0.f};
    float lsum[2] = {0.f, 0.f};

    const int srow = lane >> 3;
    const int swz  = (lane & 7) ^ srow;

    for (int kt = 0; kt < NN / 64; ++kt) {
        // stage 64 K-rows + 64 V^T d-rows (2 DMA issues each)
#pragma unroll
        for (int i = 0; i < 2; ++i) {
            int row = i * 32 + wave * 8 + srow;
            async16(Kb + (size_t)(kt * 64 + row) * rs + swz * 8,
                    &Ks[(i * 32 + wave * 8) * 64]);
            async16(Vtb + (size_t)row * NN + kt * 64 + swz * 8,
                    &Vs[(i * 32 + wave * 8) * 64]);
        }
        __syncthreads();

        // S^T = (Q K^T)^T via swapped operands; scores already exp2-domain
        f32x4 s[2][4];
#pragma unroll
        for (int nt = 0; nt < 4; ++nt) {
            const int row = nt * 16 + l16;
            bf16x8 kf0 = *(const bf16x8*)(&Ks[row * 64 + (quad ^ r7) * 8]);
            bf16x8 kf1 = *(const bf16x8*)(&Ks[row * 64 + ((quad + 4) ^ r7) * 8]);
#pragma unroll
            for (int f = 0; f < 2; ++f) {
                f32x4 z = (f32x4){0.f, 0.f, 0.f, 0.f};
                z = __builtin_amdgcn_mfma_f32_16x16x32_bf16(kf0, qf[f][0], z, 0, 0, 0);
                s[f][nt] = __builtin_amdgcn_mfma_f32_16x16x32_bf16(kf1, qf[f][1], z, 0, 0, 0);
            }
        }

        // p = exp2(s); packed b64 stores (4 consecutive keys per store)
#pragma unroll
        for (int f = 0; f < 2; ++f)
#pragma unroll
            for (int nt = 0; nt < 4; ++nt) {
                bf16x4 pk;
#pragma unroll
                for (int r = 0; r < 4; ++r) {
                    float pv = __builtin_amdgcn_exp2f(s[f][nt][r]);
                    lsum[f] += pv;
                    pk[r] = (bf16)pv;
                }
                *(bf16x4*)(&Ps[wave][(f * 16 + l16) * 72 + nt * 16 + quad * 4]) = pk;
            }
        // Ps wave-private: wave-local DS drain + compiler fence
        __asm__ volatile("s_waitcnt lgkmcnt(0)" ::: "memory");

        bf16x8 pf0[2], pf1[2];
#pragma unroll
        for (int f = 0; f < 2; ++f) {
            pf0[f] = *(const bf16x8*)(&Ps[wave][(f * 16 + l16) * 72 + quad * 8]);
            pf1[f] = *(const bf16x8*)(&Ps[wave][(f * 16 + l16) * 72 + 32 + quad * 8]);
        }
#pragma unroll
        for (int nt = 0; nt < 4; ++nt) {
            const int rowd = nt * 16 + l16;
            bf16x8 vf0 = *(const bf16x8*)(&Vs[rowd * 64 + (quad ^ r7) * 8]);
            bf16x8 vf1 = *(const bf16x8*)(&Vs[rowd * 64 + ((quad + 4) ^ r7) * 8]);
#pragma unroll
            for (int f = 0; f < 2; ++f) {
                accO[f][nt] = __builtin_amdgcn_mfma_f32_16x16x32_bf16(pf0[f], vf0, accO[f][nt], 0, 0, 0);
                accO[f][nt] = __builtin_amdgcn_mfma_f32_16x16x32_bf16(pf1[f], vf1, accO[f][nt], 0, 0, 0);
            }
        }
        __syncthreads();
    }

    // lsum: reduce over the 4 quads sharing l16 (lane's q = f*16+l16)
#pragma unroll
    for (int f = 0; f < 2; ++f) {
        lsum[f] += __shfl_xor(lsum[f], 16, 64);
        lsum[f] += __shfl_xor(lsum[f], 32, 64);
    }

    // epilogue: accO row q = f*16+quad*4+r; fetch 1/lsum from lane quad*4+r
#pragma unroll
    for (int f = 0; f < 2; ++f)
#pragma unroll
        for (int r = 0; r < 4; ++r) {
            float inv = 1.0f / __shfl(lsum[f], quad * 4 + r, 64);
            int n = qt * 128 + wave * 32 + f * 16 + quad * 4 + r;
#pragma unroll
            for (int nt = 0; nt < 4; ++nt) {
                int col = h * DD + nt * 16 + l16;
                Oqkv[(size_t)(b * NN + n) * rs + 2 * CC + col] = (bf16)(accO[f][nt][r] * inv);
            }
        }
}

// ---------------------------------------------------------------------------
extern "C" void kernel_launch(void* const* d_in, const int* in_sizes, int n_in,
                              void* d_out, int out_size, void* d_ws, size_t ws_size,
                              hipStream_t stream) {
    const float* x     = (const float*)d_in[0];
    const float* cosb  = (const float*)d_in[1];
    const float* sinb  = (const float*)d_in[2];
    const float* qkv_w = (const float*)d_in[3];
    const float* qnw   = (const float*)d_in[4];
    const float* knw   = (const float*)d_in[5];
    const float* pw    = (const float*)d_in[6];
    const float* pb    = (const float*)d_in[7];
    float* out = (float*)d_out;

    bf16* ws  = (bf16*)d_ws;
    bf16* xb  = ws + OFF_X;
    bf16* vt  = ws + OFF_VT;   // reuses xb after QKV GEMM
    bf16* qwb = ws + OFF_QW;
    bf16* pwb = ws + OFF_PW;
    bf16* qkv = ws + OFF_QKV;

    const int M = BB * NN;  // 8192

    // 0) cast MFMA operands to bf16
    convert3<<<1024, 256, 0, stream>>>(x, qkv_w, pw, ws);

    // 1) QKV projection -> qkv [B*N][3C] (bf16); 128x128 tiles
    dim3 g1(3 * CC / 128, M / 128);
    gemm128<false, bf16><<<g1, 256, 0, stream>>>(xb, CC, qwb, nullptr, qkv, M, 3 * CC, CC);

    // 2) transpose v-slice -> Vt [B*H][D][N]
    dim3 g2(BB * HH, NN / 64);
    transpose_v<<<g2, 256, 0, stream>>>(qkv, vt);

    // 3) RMSNorm + RoPE in place on q,k (q pre-scaled by CEXP)
    norm_rope<<<(BB * NN * 2 * HH) / 4, 256, 0, stream>>>(qkv, cosb, sinb, qnw, knw);

    // 4) Flash attention -> v-slice of qkv; 128 q-rows, 64-key tiles
    dim3 g4(BB * HH, NN / 128);
    flash_attn<<<g4, 256, 0, stream>>>(qkv, vt, qkv);

    // 5) Output projection (+fp32 bias) -> d_out; A = v-slice, lda = 3C
    dim3 g5(CC / 128, M / 128);
    gemm128<true, float><<<g5, 256, 0, stream>>>(qkv + 2 * CC, 3 * CC, pwb, pb, out, M, CC, CC);
}